// Round 8
// baseline (492.483 us; speedup 1.0000x reference)
//
#include <hip/hip_runtime.h>
#include <stdint.h>

// ---------------------------------------------------------------------------
// Fully-fused LocalBranch: ResNetMLP (5x GEMM+LN) + distance softmax pool,
// ONE kernel, one whole graph (128 rows) per 1024-thread block (16 waves).
// R8: vs R7 (M=32, 3 kernels): weight L2 traffic 2.0GB -> 0.5GB, Z round-trip
//     (67MB) and pool kernel deleted, per-layer overhead amortized 4x.
//     Wave tile 32x64 (acc=32) + register residual (32) fits the 128-unified
//     cap at waves_per_eu(4) -> 16 waves/CU. Pool phase in-LDS on final Xb.
// ---------------------------------------------------------------------------

typedef __attribute__((ext_vector_type(8))) short bf16x8;   // 8 bf16 = 4 VGPRs
typedef __attribute__((ext_vector_type(4))) float f32x4;

#define XB_STRIDE 264            // 256+8 pad (elems); row stride 132 dwords

__device__ __forceinline__ unsigned int rne16(float f) {
  unsigned int u = __builtin_bit_cast(unsigned int, f);
  return u + 0x7fffu + ((u >> 16) & 1u);     // RNE bf16 in high 16 bits
}
__device__ __forceinline__ unsigned short f2bf(float f) {
  return (unsigned short)(rne16(f) >> 16);
}
__device__ __forceinline__ float bf2f(unsigned short h) {
  unsigned int u = ((unsigned int)h) << 16;
  return __builtin_bit_cast(float, u);
}
__device__ __forceinline__ f32x4 zero4() {
  f32x4 v; v.x = 0.f; v.y = 0.f; v.z = 0.f; v.w = 0.f; return v;
}
// pack own bf16 (low) + lane^1 partner bf16 (high); valid on even lanes
__device__ __forceinline__ unsigned int pack_pair(float v) {
  unsigned int t = rne16(v);
  unsigned int tp = (unsigned int)__builtin_amdgcn_update_dpp(
      0, (int)t, 0xB1, 0xF, 0xF, true);                 // quad_perm xor1
  return __builtin_amdgcn_perm(tp, t, 0x07060302);
}
template <int CTRL>
__device__ __forceinline__ float dpp_add(float v) {
  int p = __builtin_amdgcn_update_dpp(0, __builtin_bit_cast(int, v),
                                      CTRL, 0xF, 0xF, true);
  return v + __builtin_bit_cast(float, p);
}
__device__ __forceinline__ float red16(float v) {  // sum over 16-lane group
  v = dpp_add<0xB1>(v);    // xor1
  v = dpp_add<0x4E>(v);    // xor2
  v = dpp_add<0x141>(v);   // row_half_mirror
  v = dpp_add<0x140>(v);   // row_mirror
  return v;
}

// ---------------------------------------------------------------------------
// Weight prep: fp32 row-major W[K][N] -> bf16 MFMA-fragment order:
//   frag f = kc*(N/16) + ntile (kc = 32-wide K slab); 64 lanes x 8 elems:
//   lane reads B[n = ntile*16 + (lane&15)][k = kc*32 + (lane>>4)*8 + e].
// ws regions (bf16 elems): stem @0 ; blocks @16384,81920,147456 ; head @212992.
// ---------------------------------------------------------------------------
__global__ void prep_weights(const float* __restrict__ Win, const float* __restrict__ Wb,
                             const float* __restrict__ Wout, unsigned short* __restrict__ ws) {
  int g = blockIdx.x * 256 + threadIdx.x;
  if (g >= 30720) return;
  const float* W; int N; int local;
  if (g < 2048) { W = Win; N = 256; local = g; }
  else if (g < 26624) {
    int i = g - 2048; int blk = i >> 13; local = i & 8191;
    W = Wb + blk * 65536; N = 256;
  } else { W = Wout; N = 128; local = g - 26624; }
  int f = local >> 6, lane = local & 63;
  int NTL = N >> 4;
  int kc = f / NTL, ntile = f - kc * NTL;
  int n = ntile * 16 + (lane & 15);
  int k0 = kc * 32 + (lane >> 4) * 8;
  unsigned short o[8];
#pragma unroll
  for (int e = 0; e < 8; ++e) o[e] = f2bf(W[(size_t)(k0 + e) * N + n]);
  *reinterpret_cast<uint4*>(ws + (size_t)g * 8) = *reinterpret_cast<uint4*>(o);
}

// ---------------------------------------------------------------------------
// One GEMM layer over 128 rows, 16 waves (4 row-groups x 4 col-groups).
// Wave tile 32 x (16*NT); NT=4 for N=256, NT=2 for N=128 (head).
// A from LDS Xb, B-frags from global (frag-packed, L2-resident), next-slab
// prefetch. MODE: 0 stem relu(ln) ; 1 residual (register carry) ; 2 head ln.
// ---------------------------------------------------------------------------
template <int KL, int N, int MODE>
__device__ __forceinline__ void layer(unsigned short* __restrict__ Xb,
                                      float* __restrict__ statQ, float* __restrict__ muR,
                                      const unsigned short* __restrict__ Wf,
                                      int tid, int wave, int lane,
                                      const float* __restrict__ bias,
                                      const float* __restrict__ gam,
                                      const float* __restrict__ bet,
                                      f32x4 (&xprev)[2][4]) {
  constexpr int NT = N / 64;         // frags per wave per k-slab
  constexpr int NTL = N / 16;        // 16-col tiles across N
  constexpr int KC = KL / 32;        // 32-wide K slabs
  const int wr = wave >> 2, wc = wave & 3;
  const int q = lane >> 4, l16 = lane & 15;
  const int rowbase = wr * 32;
  const int colbase = wc * 16 * NT;
  const unsigned short* Wl = Wf + lane * 8;

  f32x4 acc[2][NT];
#pragma unroll
  for (int mt = 0; mt < 2; ++mt)
#pragma unroll
    for (int nt = 0; nt < NT; ++nt) acc[mt][nt] = zero4();

  bf16x8 bcur[NT];
#pragma unroll
  for (int nt = 0; nt < NT; ++nt)    // prefetch slab 0 before the barrier
    bcur[nt] = *reinterpret_cast<const bf16x8*>(Wl + (size_t)(wc * NT + nt) * 512);

  __syncthreads();                   // B1: Xb from prev layer ready
#pragma unroll
  for (int kc = 0; kc < KC; ++kc) {
    bf16x8 bnext[NT];
    if (kc + 1 < KC) {
#pragma unroll
      for (int nt = 0; nt < NT; ++nt)
        bnext[nt] = *reinterpret_cast<const bf16x8*>(
            Wl + (size_t)((kc + 1) * NTL + wc * NT + nt) * 512);
    }
    const int kk = kc * 32 + q * 8;
    bf16x8 a0 = *reinterpret_cast<const bf16x8*>(Xb + (rowbase + l16) * XB_STRIDE + kk);
    bf16x8 a1 = *reinterpret_cast<const bf16x8*>(Xb + (rowbase + 16 + l16) * XB_STRIDE + kk);
#pragma unroll
    for (int nt = 0; nt < NT; ++nt)
      acc[0][nt] = __builtin_amdgcn_mfma_f32_16x16x32_bf16(a0, bcur[nt], acc[0][nt], 0, 0, 0);
#pragma unroll
    for (int nt = 0; nt < NT; ++nt)
      acc[1][nt] = __builtin_amdgcn_mfma_f32_16x16x32_bf16(a1, bcur[nt], acc[1][nt], 0, 0, 0);
    if (kc + 1 < KC) {
#pragma unroll
      for (int nt = 0; nt < NT; ++nt) bcur[nt] = bnext[nt];
    }
  }

  // ---- epilogue: bias, per-row stats (DPP over 16 lanes, LDS across wc)
  float bcol[NT], gcol[NT], becol[NT];
#pragma unroll
  for (int nt = 0; nt < NT; ++nt) {
    int col = colbase + 16 * nt + l16;
    bcol[nt] = bias[col]; gcol[nt] = gam[col]; becol[nt] = bet[col];
  }
#pragma unroll
  for (int mt = 0; mt < 2; ++mt) {
#pragma unroll
    for (int nt = 0; nt < NT; ++nt) {
      acc[mt][nt].x += bcol[nt]; acc[mt][nt].y += bcol[nt];
      acc[mt][nt].z += bcol[nt]; acc[mt][nt].w += bcol[nt];
    }
    f32x4 s1 = acc[mt][0];
    f32x4 s2 = acc[mt][0] * acc[mt][0];
#pragma unroll
    for (int nt = 1; nt < NT; ++nt) { s1 += acc[mt][nt]; s2 += acc[mt][nt] * acc[mt][nt]; }
#pragma unroll
    for (int r = 0; r < 4; ++r) { s1[r] = red16(s1[r]); s2[r] = red16(s2[r]); }
    if (l16 == 0) {                  // rows rowbase+16mt+4q+r ; stride-9 pad
#pragma unroll
      for (int r = 0; r < 4; ++r) {
        int row = rowbase + 16 * mt + 4 * q + r;
        float2 o; o.x = s1[r]; o.y = s2[r];
        *reinterpret_cast<float2*>(statQ + row * 9 + 2 * wc) = o;
      }
    }
  }
  __syncthreads();                   // B2: stats published
  if (tid < 128) {                   // per-row cross-wc reduce -> (mu,rstd)
    float S1 = 0.f, S2 = 0.f;
#pragma unroll
    for (int w = 0; w < 4; ++w) {
      float2 v = *reinterpret_cast<const float2*>(statQ + tid * 9 + 2 * w);
      S1 += v.x; S2 += v.y;
    }
    float mu = S1 * (1.0f / N);
    float var = S2 * (1.0f / N) - mu * mu;
    float rstd = rsqrtf(var + 1e-5f);
    float2 o; o.x = mu; o.y = rstd;
    *reinterpret_cast<float2*>(muR + 2 * tid) = o;
  }
  __syncthreads();                   // B3: (mu,rstd) ready
  unsigned int* Xw = reinterpret_cast<unsigned int*>(Xb);
#pragma unroll
  for (int mt = 0; mt < 2; ++mt)
#pragma unroll
    for (int r = 0; r < 4; ++r) {
      const int row = rowbase + 16 * mt + 4 * q + r;
      float2 m = *reinterpret_cast<const float2*>(muR + 2 * row);   // broadcast
      const float nmr = -m.x * m.y;
#pragma unroll
      for (int nt = 0; nt < NT; ++nt) {
        float z = __builtin_fmaf(acc[mt][nt][r], m.y, nmr);
        float o = __builtin_fmaf(z, gcol[nt], becol[nt]);
        float xv;
        if constexpr (MODE == 0) { xv = fmaxf(o, 0.f); xprev[mt][nt][r] = xv; }
        else if constexpr (MODE == 1) {
          xv = xprev[mt][nt][r] + fmaxf(o, 0.f); xprev[mt][nt][r] = xv;
        } else { xv = o; }
        unsigned int pk = pack_pair(xv);
        if ((l16 & 1) == 0)
          Xw[row * 132 + ((colbase + 16 * nt + l16) >> 1)] = pk;
      }
    }
}

// ---------------------------------------------------------------------------
// Fused kernel: one graph per block, 1024 thr (16 waves).
// ---------------------------------------------------------------------------
__global__ __attribute__((amdgpu_flat_work_group_size(1024, 1024), amdgpu_waves_per_eu(4)))
void fused_main(const float* __restrict__ H, const unsigned short* __restrict__ ws,
                const float* __restrict__ b_in, const float* __restrict__ g_in,
                const float* __restrict__ beta_in,
                const float* __restrict__ bb, const float* __restrict__ gb,
                const float* __restrict__ betab,
                const float* __restrict__ b_out, const float* __restrict__ g_out,
                const float* __restrict__ beta_out,
                float* __restrict__ out) {
  __shared__ __attribute__((aligned(16))) unsigned short Xb[128 * XB_STRIDE];
  __shared__ __attribute__((aligned(16))) float statQ[128 * 9 + 8];
  __shared__ __attribute__((aligned(16))) float muR[256];
  __shared__ float sqv[128], sm[128], smw[128];
  const int tid = threadIdx.x;
  const int g = blockIdx.x;
  const int wave = tid >> 6, lane = tid & 63;
  const int q = lane >> 4, l16 = lane & 15;

  // stage H (128 x 64 fp32) -> Xb bf16 ; 8 values/thread, packed b128 store
  {
    int row = tid >> 3, c8 = (tid & 7) * 8;
    const float4* hp = reinterpret_cast<const float4*>(
        H + ((size_t)g * 128 + row) * 64 + c8);
    float4 fa = hp[0], fb = hp[1];
    uint4 o;
    o.x = __builtin_amdgcn_perm(rne16(fa.y), rne16(fa.x), 0x07060302);
    o.y = __builtin_amdgcn_perm(rne16(fa.w), rne16(fa.z), 0x07060302);
    o.z = __builtin_amdgcn_perm(rne16(fb.y), rne16(fb.x), 0x07060302);
    o.w = __builtin_amdgcn_perm(rne16(fb.w), rne16(fb.z), 0x07060302);
    *reinterpret_cast<uint4*>(Xb + row * XB_STRIDE + c8) = o;
  }

  f32x4 xprev[2][4];
  layer<64, 256, 0>(Xb, statQ, muR, ws,           tid, wave, lane, b_in,     g_in,     beta_in,  xprev);
  layer<256, 256, 1>(Xb, statQ, muR, ws + 16384,  tid, wave, lane, bb,       gb,       betab,    xprev);
  layer<256, 256, 1>(Xb, statQ, muR, ws + 81920,  tid, wave, lane, bb + 256, gb + 256, betab + 256, xprev);
  layer<256, 256, 1>(Xb, statQ, muR, ws + 147456, tid, wave, lane, bb + 512, gb + 512, betab + 512, xprev);
  layer<256, 128, 2>(Xb, statQ, muR, ws + 212992, tid, wave, lane, b_out,    g_out,    beta_out, xprev);
  __syncthreads();                   // Z (bf16, Xb cols 0..127) ready

  // ---- pool phase: gram + mean-distance + softmax + weighted sum
  // waves 0..7 do the gram (16 rows x 128 each); all waves hit the barriers.
  f32x4 g2[8];
#pragma unroll
  for (int nt = 0; nt < 8; ++nt) g2[nt] = zero4();
  if (wave < 8) {
#pragma unroll
    for (int ks = 0; ks < 4; ++ks) {
      int kk = ks * 32 + q * 8;
      bf16x8 a = *reinterpret_cast<const bf16x8*>(Xb + (16 * wave + l16) * XB_STRIDE + kk);
#pragma unroll
      for (int nt = 0; nt < 8; ++nt) {
        bf16x8 bfr = *reinterpret_cast<const bf16x8*>(Xb + (16 * nt + l16) * XB_STRIDE + kk);
        g2[nt] = __builtin_amdgcn_mfma_f32_16x16x32_bf16(a, bfr, g2[nt], 0, 0, 0);
      }
    }
    // publish sq_i = G_ii (diag) so d_ii == sqrt(1e-12) exactly like ref
    if ((l16 >> 2) == q) {
#pragma unroll
      for (int nt = 0; nt < 8; ++nt)
        if (nt == wave) {
#pragma unroll
          for (int r = 0; r < 4; ++r)
            if ((l16 & 3) == r) sqv[16 * wave + l16] = g2[nt][r];
        }
    }
  }
  __syncthreads();
  if (wave < 8) {                    // distances, s_i = mean_j d_ij
    float sqi[4];
#pragma unroll
    for (int r = 0; r < 4; ++r) sqi[r] = sqv[16 * wave + q * 4 + r];
    float sp[4] = {0.f, 0.f, 0.f, 0.f};
#pragma unroll
    for (int nt = 0; nt < 8; ++nt) {
      float sqj = sqv[16 * nt + l16];
#pragma unroll
      for (int r = 0; r < 4; ++r) {
        float d2 = sqi[r] + sqj - 2.0f * g2[nt][r];
        sp[r] += sqrtf(fmaxf(d2, 0.f) + 1e-12f);
      }
    }
#pragma unroll
    for (int d = 1; d < 16; d <<= 1) {
#pragma unroll
      for (int r = 0; r < 4; ++r) { float t = sp[r]; t += __shfl_xor(t, d); sp[r] = t; }
    }
    if (l16 == 0) {
#pragma unroll
      for (int r = 0; r < 4; ++r) sm[16 * wave + q * 4 + r] = sp[r] * (1.0f / 128.0f);
    }
  }
  __syncthreads();
  if (wave == 0) {                   // softmax(s/TAU), 1/TAU = 4
    float l0 = sm[lane] * 4.0f;
    float l1 = sm[lane + 64] * 4.0f;
    float mx = fmaxf(l0, l1);
#pragma unroll
    for (int d = 1; d < 64; d <<= 1) mx = fmaxf(mx, __shfl_xor(mx, d));
    float e0 = __expf(l0 - mx), e1 = __expf(l1 - mx);
    float ss = e0 + e1;
#pragma unroll
    for (int d = 1; d < 64; d <<= 1) ss += __shfl_xor(ss, d);
    float inv = 1.0f / ss;
    float w0 = e0 * inv, w1 = e1 * inv;
    smw[lane] = w0;
    smw[lane + 64] = w1;
    out[131072 + g * 128 + lane] = w0;
    out[131072 + g * 128 + 64 + lane] = w1;
  }
  __syncthreads();
  if (wave < 8) {                    // v_loc = sum_i w_i * Z[i,:]
    int c = 16 * wave + l16;
    float acv = 0.f;
#pragma unroll
    for (int i0 = 0; i0 < 32; ++i0) {
      int i = q * 32 + i0;
      acv += smw[i] * bf2f(Xb[i * XB_STRIDE + c]);
    }
    acv += __shfl_xor(acv, 16);
    acv += __shfl_xor(acv, 32);
    if (q == 0) out[g * 128 + c] = acv;
  }
}

// ---------------------------------------------------------------------------
extern "C" void kernel_launch(void* const* d_in, const int* in_sizes, int n_in,
                              void* d_out, int out_size, void* d_ws, size_t ws_size,
                              hipStream_t stream) {
  (void)in_sizes; (void)n_in; (void)out_size; (void)ws_size;
  const float* H        = (const float*)d_in[0];
  // d_in[1] = batch_ptr (uniform 128/graph, unused)
  const float* W_in     = (const float*)d_in[2];
  const float* b_in     = (const float*)d_in[3];
  const float* g_in     = (const float*)d_in[4];
  const float* beta_in  = (const float*)d_in[5];
  const float* Wb       = (const float*)d_in[6];
  const float* bb       = (const float*)d_in[7];
  const float* gb       = (const float*)d_in[8];
  const float* betab    = (const float*)d_in[9];
  const float* W_out    = (const float*)d_in[10];
  const float* b_out    = (const float*)d_in[11];
  const float* g_out    = (const float*)d_in[12];
  const float* beta_out = (const float*)d_in[13];
  float* out = (float*)d_out;
  unsigned short* ws = (unsigned short*)d_ws;

  prep_weights<<<120, 256, 0, stream>>>(W_in, Wb, W_out, ws);
  fused_main<<<1024, 1024, 0, stream>>>(H, ws, b_in, g_in, beta_in,
                                        bb, gb, betab, b_out, g_out, beta_out, out);
}

// Round 9
// 255.380 us; speedup vs baseline: 1.9284x; 1.9284x over previous
//
#include <hip/hip_runtime.h>
#include <stdint.h>

// ---------------------------------------------------------------------------
// LocalBranch: ResNetMLP (5x GEMM+LN) + per-graph distance softmax pool.
// R9: half-graph blocks (2048 x 1024thr, M=64), R7's per-thread register
//     shape (acc16+carry16+prefetch16 <= 96 data regs, the hard cap learned
//     in R4/R8). Row-domain LN epilogue via fp32 Yb bounce:
//       phase A: 16 b32 LDS writes of raw acc (stride 260 -> 2-way, free)
//       phase B: thread owns (row, 16 contiguous cols): 4 b128 reads,
//                fma-chain stats, ONE red16 of 2 values, within-thread
//                v_perm bf16 pair packing, register residual (row domain).
//     Kills R7's 128-inst/layer red16 + dpp pack (~19 -> ~12 VALU/value).
//     Params staged to LDS per layer; weight L2 traffic 2GB -> 1GB.
// ---------------------------------------------------------------------------

typedef __attribute__((ext_vector_type(8))) short bf16x8;   // 8 bf16 = 4 VGPRs
typedef __attribute__((ext_vector_type(4))) float f32x4;

#define XB_STRIDE 264            // bf16 elems; 132 dwords/row
#define YB_STRIDE 260            // fp32; 260*4=1040B -> 4-row q-step = 16 banks
#define ZB_STRIDE 136            // pool Z tile 128+8
#define LDS_YB    33792          // byte offset (Xb = 64*264*2 = 33792)
#define LDS_PAR   100352         // 33792 + 64*260*4 (=66560)
#define LDS_TOTAL 103424         // + 768*4

__device__ __forceinline__ unsigned int rne16(float f) {
  unsigned int u = __builtin_bit_cast(unsigned int, f);
  return u + 0x7fffu + ((u >> 16) & 1u);     // RNE bf16 in high 16 bits
}
__device__ __forceinline__ unsigned short f2bf(float f) {
  return (unsigned short)(rne16(f) >> 16);
}
__device__ __forceinline__ float bf2f(unsigned short h) {
  unsigned int u = ((unsigned int)h) << 16;
  return __builtin_bit_cast(float, u);
}
__device__ __forceinline__ f32x4 zero4() {
  f32x4 v; v.x = 0.f; v.y = 0.f; v.z = 0.f; v.w = 0.f; return v;
}
template <int CTRL>
__device__ __forceinline__ float dpp_add(float v) {
  int p = __builtin_amdgcn_update_dpp(0, __builtin_bit_cast(int, v),
                                      CTRL, 0xF, 0xF, true);
  return v + __builtin_bit_cast(float, p);
}
__device__ __forceinline__ float red16(float v) {  // sum over 16-lane group
  v = dpp_add<0xB1>(v);    // xor1
  v = dpp_add<0x4E>(v);    // xor2
  v = dpp_add<0x141>(v);   // row_half_mirror
  v = dpp_add<0x140>(v);   // row_mirror
  return v;
}

// ---------------------------------------------------------------------------
// Weight prep: fp32 row-major W[K][N] -> bf16 MFMA-fragment order:
//   frag f = kc*(N/16) + ntile (kc = 32-wide K slab); 64 lanes x 8 elems:
//   lane reads B[n = ntile*16 + (lane&15)][k = kc*32 + (lane>>4)*8 + e].
// ws regions (bf16 elems): stem @0 ; blocks @16384,81920,147456 ; head @212992 ;
// Z buffer @262144 (1024*128*128).
// ---------------------------------------------------------------------------
__global__ void prep_weights(const float* __restrict__ Win, const float* __restrict__ Wb,
                             const float* __restrict__ Wout, unsigned short* __restrict__ ws) {
  int g = blockIdx.x * 256 + threadIdx.x;
  if (g >= 30720) return;
  const float* W; int N; int local;
  if (g < 2048) { W = Win; N = 256; local = g; }
  else if (g < 26624) {
    int i = g - 2048; int blk = i >> 13; local = i & 8191;
    W = Wb + blk * 65536; N = 256;
  } else { W = Wout; N = 128; local = g - 26624; }
  int f = local >> 6, lane = local & 63;
  int NTL = N >> 4;
  int kc = f / NTL, ntile = f - kc * NTL;
  int n = ntile * 16 + (lane & 15);
  int k0 = kc * 32 + (lane >> 4) * 8;
  unsigned short o[8];
#pragma unroll
  for (int e = 0; e < 8; ++e) o[e] = f2bf(W[(size_t)(k0 + e) * N + n]);
  *reinterpret_cast<uint4*>(ws + (size_t)g * 8) = *reinterpret_cast<uint4*>(o);
}

// ---------------------------------------------------------------------------
// One GEMM layer over 64 rows, 16 waves (2 row-groups x 8 col-groups).
// Wave tile 32 x (16*NT); NT=2 for N=256, NT=1 for N=128.
// MODE: 0 stem relu(ln) ; 1 residual (row-domain register carry) ; 2 head ->
// writes z straight to global Z (no Xb store).
// ---------------------------------------------------------------------------
template <int KL, int N, int MODE>
__device__ __forceinline__ void layer(unsigned short* __restrict__ Xb,
                                      float* __restrict__ Yb, float* __restrict__ par,
                                      const unsigned short* __restrict__ Wf,
                                      int tid, int wave, int lane,
                                      const float* __restrict__ bias,
                                      const float* __restrict__ gam,
                                      const float* __restrict__ bet,
                                      float (&xprev)[16],
                                      unsigned short* __restrict__ Z, size_t rowglob) {
  constexpr int NT = N / 128;        // frags per wave per k-slab
  constexpr int NTL = N / 16;        // 16-col tiles across N
  constexpr int KC = KL / 32;        // 32-wide K slabs
  constexpr int CPT = N / 16;        // cols per thread in phase B (16 or 8)
  const int wr = wave >> 3, wc = wave & 7;
  const int q = lane >> 4, l16 = lane & 15;
  const int rowbase = wr * 32;
  const int colbase = wc * 16 * NT;
  const unsigned short* Wl = Wf + lane * 8;

  f32x4 acc[2][NT];
#pragma unroll
  for (int mt = 0; mt < 2; ++mt)
#pragma unroll
    for (int nt = 0; nt < NT; ++nt) acc[mt][nt] = zero4();

  bf16x8 bcur[NT];
#pragma unroll
  for (int nt = 0; nt < NT; ++nt)    // prefetch slab 0 before the barrier
    bcur[nt] = *reinterpret_cast<const bf16x8*>(Wl + (size_t)(wc * NT + nt) * 512);

  __syncthreads();                   // B1: prev phase-B done (Xb/par reusable)
  // stage params (bias|gamma|beta) -> LDS, read in phase B after B2
  if (tid < 3 * N) {
    float v = (tid < N) ? bias[tid] : (tid < 2 * N) ? gam[tid - N] : bet[tid - 2 * N];
    par[tid] = v;
  }
#pragma unroll
  for (int kc = 0; kc < KC; ++kc) {
    bf16x8 bnext[NT];
    if (kc + 1 < KC) {
#pragma unroll
      for (int nt = 0; nt < NT; ++nt)
        bnext[nt] = *reinterpret_cast<const bf16x8*>(
            Wl + (size_t)((kc + 1) * NTL + wc * NT + nt) * 512);
    }
    const int kk = kc * 32 + q * 8;
    bf16x8 a0 = *reinterpret_cast<const bf16x8*>(Xb + (rowbase + l16) * XB_STRIDE + kk);
    bf16x8 a1 = *reinterpret_cast<const bf16x8*>(Xb + (rowbase + 16 + l16) * XB_STRIDE + kk);
#pragma unroll
    for (int nt = 0; nt < NT; ++nt)
      acc[0][nt] = __builtin_amdgcn_mfma_f32_16x16x32_bf16(a0, bcur[nt], acc[0][nt], 0, 0, 0);
#pragma unroll
    for (int nt = 0; nt < NT; ++nt)
      acc[1][nt] = __builtin_amdgcn_mfma_f32_16x16x32_bf16(a1, bcur[nt], acc[1][nt], 0, 0, 0);
    if (kc + 1 < KC) {
#pragma unroll
      for (int nt = 0; nt < NT; ++nt) bcur[nt] = bnext[nt];
    }
  }

  // ---- phase A: raw acc -> Yb fp32 (C-layout scatter; 2-way conflicts only)
#pragma unroll
  for (int mt = 0; mt < 2; ++mt)
#pragma unroll
    for (int nt = 0; nt < NT; ++nt) {
      const int col = colbase + 16 * nt + l16;
#pragma unroll
      for (int r = 0; r < 4; ++r)
        Yb[(rowbase + 16 * mt + 4 * q + r) * YB_STRIDE + col] = acc[mt][nt][r];
    }
  __syncthreads();                   // B2: Yb + par complete; K-loop Xb reads done

  // ---- phase B: row-domain LN. thread = (row = wave*4+q, cols l16*CPT..+CPT-1)
  const int row = wave * 4 + q;
  const int c0 = l16 * CPT;
  float y[CPT];
#pragma unroll
  for (int j = 0; j < CPT / 4; ++j)
    *reinterpret_cast<f32x4*>(y + 4 * j) =
        *reinterpret_cast<const f32x4*>(Yb + row * YB_STRIDE + c0 + 4 * j);
  float bv[CPT], gv[CPT], ev[CPT];
#pragma unroll
  for (int j = 0; j < CPT / 4; ++j) {
    *reinterpret_cast<f32x4*>(bv + 4 * j) = *reinterpret_cast<const f32x4*>(par + c0 + 4 * j);
    *reinterpret_cast<f32x4*>(gv + 4 * j) = *reinterpret_cast<const f32x4*>(par + N + c0 + 4 * j);
    *reinterpret_cast<f32x4*>(ev + 4 * j) = *reinterpret_cast<const f32x4*>(par + 2 * N + c0 + 4 * j);
  }
  float s1 = 0.f, s2 = 0.f;
#pragma unroll
  for (int e = 0; e < CPT; ++e) {
    y[e] += bv[e];
    s1 += y[e]; s2 = __builtin_fmaf(y[e], y[e], s2);
  }
  s1 = red16(s1); s2 = red16(s2);
  const float mu = s1 * (1.0f / N);
  const float var = s2 * (1.0f / N) - mu * mu;
  const float rstd = rsqrtf(var + 1e-5f);
  const float nmr = -mu * rstd;
  unsigned int pk[CPT / 2];
#pragma unroll
  for (int e = 0; e < CPT; ++e) {
    float t = __builtin_fmaf(y[e], rstd, nmr);
    float o = __builtin_fmaf(t, gv[e], ev[e]);
    float xv;
    if constexpr (MODE == 0) { xv = fmaxf(o, 0.f); xprev[e] = xv; }
    else if constexpr (MODE == 1) { xv = xprev[e] + fmaxf(o, 0.f); xprev[e] = xv; }
    else { xv = o; }
    if (e & 1)
      pk[e >> 1] = __builtin_amdgcn_perm(rne16(xv), rne16(__builtin_bit_cast(float, pk[e >> 1])),
                                         0x07060302);
    else
      pk[e >> 1] = __builtin_bit_cast(unsigned int, xv);
  }
  if constexpr (MODE != 2) {         // store bf16 row back to Xb (2 b128)
    unsigned int* Xw = reinterpret_cast<unsigned int*>(Xb);
#pragma unroll
    for (int j = 0; j < CPT / 8; ++j)
      *reinterpret_cast<uint4*>(Xw + row * 132 + (c0 >> 1) + 4 * j) =
          *reinterpret_cast<uint4*>(pk + 4 * j);
  } else {                           // head: z -> global Z (16B per thread)
    *reinterpret_cast<uint4*>(Z + (rowglob + row) * 128 + c0) =
        *reinterpret_cast<uint4*>(pk);
  }
}

// ---------------------------------------------------------------------------
// Kernel 1: ResNetMLP over 64 rows (half graph). 2048 blocks x 1024 thr.
// ---------------------------------------------------------------------------
__global__ __attribute__((amdgpu_flat_work_group_size(1024, 1024), amdgpu_waves_per_eu(4)))
void mlp_main(const float* __restrict__ H, const unsigned short* __restrict__ ws,
              const float* __restrict__ b_in, const float* __restrict__ g_in,
              const float* __restrict__ beta_in,
              const float* __restrict__ bb, const float* __restrict__ gb,
              const float* __restrict__ betab,
              const float* __restrict__ b_out, const float* __restrict__ g_out,
              const float* __restrict__ beta_out,
              unsigned short* __restrict__ Z) {
  extern __shared__ char smem[];
  unsigned short* Xb = (unsigned short*)smem;
  float* Yb = (float*)(smem + LDS_YB);
  float* par = (float*)(smem + LDS_PAR);
  const int tid = threadIdx.x;
  const int wave = tid >> 6, lane = tid & 63;
  const size_t rowglob = (size_t)blockIdx.x * 64;

  // stage H (64 x 64 fp32) -> Xb bf16 ; 4 values/thread, packed b64 store
  {
    int row = tid >> 4, c4 = (tid & 15) * 4;
    float4 f = *reinterpret_cast<const float4*>(H + (rowglob + row) * 64 + c4);
    uint2 o;
    o.x = __builtin_amdgcn_perm(rne16(f.y), rne16(f.x), 0x07060302);
    o.y = __builtin_amdgcn_perm(rne16(f.w), rne16(f.z), 0x07060302);
    *reinterpret_cast<uint2*>(Xb + row * XB_STRIDE + c4) = o;
  }

  float xprev[16];
  layer<64, 256, 0>(Xb, Yb, par, ws,           tid, wave, lane, b_in,     g_in,     beta_in,  xprev, Z, rowglob);
  layer<256, 256, 1>(Xb, Yb, par, ws + 16384,  tid, wave, lane, bb,       gb,       betab,    xprev, Z, rowglob);
  layer<256, 256, 1>(Xb, Yb, par, ws + 81920,  tid, wave, lane, bb + 256, gb + 256, betab + 256, xprev, Z, rowglob);
  layer<256, 256, 1>(Xb, Yb, par, ws + 147456, tid, wave, lane, bb + 512, gb + 512, betab + 512, xprev, Z, rowglob);
  layer<256, 128, 2>(Xb, Yb, par, ws + 212992, tid, wave, lane, b_out,    g_out,    beta_out, xprev, Z, rowglob);
}

// ---------------------------------------------------------------------------
// Kernel 2: per-graph gram + mean-distance + softmax + weighted pool.
// 1024 blocks x 512 thr; Z[g] (128x128 bf16) staged to LDS. (R7-verified.)
// ---------------------------------------------------------------------------
__global__ __attribute__((amdgpu_flat_work_group_size(512, 512)))
void pool_main(const unsigned short* __restrict__ Z, float* __restrict__ out) {
  __shared__ unsigned short Zb[128 * ZB_STRIDE];
  __shared__ float sqv[128], sm[128], smw[128];
  const int tid = threadIdx.x;
  const int g = blockIdx.x;
  const int wave = tid >> 6, lane = tid & 63;
  const int q = lane >> 4, l16 = lane & 15;

  {
    int zr = tid >> 2, zc = (tid & 3) * 32;
    const uint4* zp = reinterpret_cast<const uint4*>(Z + ((size_t)g * 128 + zr) * 128 + zc);
    uint4* zd = reinterpret_cast<uint4*>(Zb + zr * ZB_STRIDE + zc);
    zd[0] = zp[0]; zd[1] = zp[1]; zd[2] = zp[2]; zd[3] = zp[3];
  }
  __syncthreads();

  // gram G = Z Z^T : wave owns 16 rows x 128 cols
  f32x4 g2[8];
#pragma unroll
  for (int nt = 0; nt < 8; ++nt) g2[nt] = zero4();
#pragma unroll
  for (int ks = 0; ks < 4; ++ks) {
    int kk = ks * 32 + q * 8;
    bf16x8 a = *reinterpret_cast<const bf16x8*>(Zb + (16 * wave + l16) * ZB_STRIDE + kk);
#pragma unroll
    for (int nt = 0; nt < 8; ++nt) {
      bf16x8 bfr = *reinterpret_cast<const bf16x8*>(Zb + (16 * nt + l16) * ZB_STRIDE + kk);
      g2[nt] = __builtin_amdgcn_mfma_f32_16x16x32_bf16(a, bfr, g2[nt], 0, 0, 0);
    }
  }
  // publish sq_i = G_ii (diag) so d_ii == sqrt(1e-12) exactly like ref
  if ((l16 >> 2) == q) {
#pragma unroll
    for (int nt = 0; nt < 8; ++nt)
      if (nt == wave) {
#pragma unroll
        for (int r = 0; r < 4; ++r)
          if ((l16 & 3) == r) sqv[16 * wave + l16] = g2[nt][r];
      }
  }
  __syncthreads();
  // distances and s_i = mean_j d_ij
  float sqi[4];
#pragma unroll
  for (int r = 0; r < 4; ++r) sqi[r] = sqv[16 * wave + q * 4 + r];
  float sp[4] = {0.f, 0.f, 0.f, 0.f};
#pragma unroll
  for (int nt = 0; nt < 8; ++nt) {
    float sqj = sqv[16 * nt + l16];
#pragma unroll
    for (int r = 0; r < 4; ++r) {
      float d2 = sqi[r] + sqj - 2.0f * g2[nt][r];
      sp[r] += sqrtf(fmaxf(d2, 0.f) + 1e-12f);
    }
  }
#pragma unroll
  for (int d = 1; d < 16; d <<= 1) {
#pragma unroll
    for (int r = 0; r < 4; ++r) { float t = sp[r]; t += __shfl_xor(t, d); sp[r] = t; }
  }
  if (l16 == 0) {
#pragma unroll
    for (int r = 0; r < 4; ++r) sm[16 * wave + q * 4 + r] = sp[r] * (1.0f / 128.0f);
  }
  __syncthreads();
  // softmax(s/TAU) by wave 0 (1/TAU = 4)
  if (wave == 0) {
    float l0 = sm[lane] * 4.0f;
    float l1 = sm[lane + 64] * 4.0f;
    float mx = fmaxf(l0, l1);
#pragma unroll
    for (int d = 1; d < 64; d <<= 1) mx = fmaxf(mx, __shfl_xor(mx, d));
    float e0 = __expf(l0 - mx), e1 = __expf(l1 - mx);
    float ss = e0 + e1;
#pragma unroll
    for (int d = 1; d < 64; d <<= 1) ss += __shfl_xor(ss, d);
    float inv = 1.0f / ss;
    float w0 = e0 * inv, w1 = e1 * inv;
    smw[lane] = w0;
    smw[lane + 64] = w1;
    out[131072 + g * 128 + lane] = w0;
    out[131072 + g * 128 + 64 + lane] = w1;
  }
  __syncthreads();
  // v_loc = sum_i w_i * Z[i,:]
  {
    int c = 16 * wave + l16;
    float acv = 0.f;
#pragma unroll
    for (int i0 = 0; i0 < 32; ++i0) {
      int i = q * 32 + i0;
      acv += smw[i] * bf2f(Zb[i * ZB_STRIDE + c]);
    }
    acv += __shfl_xor(acv, 16);
    acv += __shfl_xor(acv, 32);
    if (q == 0) out[g * 128 + c] = acv;
  }
}

// ---------------------------------------------------------------------------
extern "C" void kernel_launch(void* const* d_in, const int* in_sizes, int n_in,
                              void* d_out, int out_size, void* d_ws, size_t ws_size,
                              hipStream_t stream) {
  (void)in_sizes; (void)n_in; (void)out_size; (void)ws_size;
  const float* H        = (const float*)d_in[0];
  // d_in[1] = batch_ptr (uniform 128/graph, unused)
  const float* W_in     = (const float*)d_in[2];
  const float* b_in     = (const float*)d_in[3];
  const float* g_in     = (const float*)d_in[4];
  const float* beta_in  = (const float*)d_in[5];
  const float* Wb       = (const float*)d_in[6];
  const float* bb       = (const float*)d_in[7];
  const float* gb       = (const float*)d_in[8];
  const float* betab    = (const float*)d_in[9];
  const float* W_out    = (const float*)d_in[10];
  const float* b_out    = (const float*)d_in[11];
  const float* g_out    = (const float*)d_in[12];
  const float* beta_out = (const float*)d_in[13];
  float* out = (float*)d_out;
  unsigned short* ws = (unsigned short*)d_ws;
  unsigned short* Z = ws + 262144;      // 1024*128*128 bf16 = 33.5 MB

  prep_weights<<<120, 256, 0, stream>>>(W_in, Wb, W_out, ws);
  hipFuncSetAttribute(reinterpret_cast<const void*>(mlp_main),
                      hipFuncAttributeMaxDynamicSharedMemorySize, LDS_TOTAL);
  mlp_main<<<2048, 1024, LDS_TOTAL, stream>>>(H, ws, b_in, g_in, beta_in,
                                              bb, gb, betab, b_out, g_out, beta_out, Z);
  pool_main<<<1024, 512, 0, stream>>>(Z, out);
}

// Round 10
// 234.733 us; speedup vs baseline: 2.0981x; 1.0880x over previous
//
#include <hip/hip_runtime.h>
#include <stdint.h>

// ---------------------------------------------------------------------------
// LocalBranch: ResNetMLP (5x GEMM+LN) + per-graph distance softmax pool.
// R10 = R9 + swizzled phase-B column map. R9's c0=l16*16 put all 16 lanes on
//     2 of 8 four-bank groups (3.28e7 conflict cycles ~= 32% of block time).
//     New map: thread (row, cols {l16*4 + 64j}) -> bank residue 4(q+l16)%32,
//     uniform (b128 floor). Xb stores b64 at 2(2q+l16)%32, uniform.
//     1 block/CU is structural for 1024-thr blocks (2 blocks would need <=64
//     unified regs/wave); fp32 Yb stays (LDS is not the binding resource).
// ---------------------------------------------------------------------------

typedef __attribute__((ext_vector_type(8))) short bf16x8;   // 8 bf16 = 4 VGPRs
typedef __attribute__((ext_vector_type(4))) float f32x4;

#define XB_STRIDE 264            // bf16 elems; 132 dwords/row
#define YB_STRIDE 260            // fp32; row step == 4 banks
#define ZB_STRIDE 136            // pool Z tile 128+8
#define LDS_YB    33792          // byte offset (Xb = 64*264*2 = 33792)
#define LDS_PAR   100352         // 33792 + 64*260*4 (=66560)
#define LDS_TOTAL 103424         // + 768*4

__device__ __forceinline__ unsigned int rne16(float f) {
  unsigned int u = __builtin_bit_cast(unsigned int, f);
  return u + 0x7fffu + ((u >> 16) & 1u);     // RNE bf16 in high 16 bits
}
__device__ __forceinline__ unsigned short f2bf(float f) {
  return (unsigned short)(rne16(f) >> 16);
}
__device__ __forceinline__ float bf2f(unsigned short h) {
  unsigned int u = ((unsigned int)h) << 16;
  return __builtin_bit_cast(float, u);
}
__device__ __forceinline__ f32x4 zero4() {
  f32x4 v; v.x = 0.f; v.y = 0.f; v.z = 0.f; v.w = 0.f; return v;
}
template <int CTRL>
__device__ __forceinline__ float dpp_add(float v) {
  int p = __builtin_amdgcn_update_dpp(0, __builtin_bit_cast(int, v),
                                      CTRL, 0xF, 0xF, true);
  return v + __builtin_bit_cast(float, p);
}
__device__ __forceinline__ float red16(float v) {  // sum over 16-lane group
  v = dpp_add<0xB1>(v);    // xor1
  v = dpp_add<0x4E>(v);    // xor2
  v = dpp_add<0x141>(v);   // row_half_mirror
  v = dpp_add<0x140>(v);   // row_mirror
  return v;
}

// ---------------------------------------------------------------------------
// Weight prep: fp32 row-major W[K][N] -> bf16 MFMA-fragment order:
//   frag f = kc*(N/16) + ntile (kc = 32-wide K slab); 64 lanes x 8 elems:
//   lane reads B[n = ntile*16 + (lane&15)][k = kc*32 + (lane>>4)*8 + e].
// ws regions (bf16 elems): stem @0 ; blocks @16384,81920,147456 ; head @212992 ;
// Z buffer @262144 (1024*128*128).
// ---------------------------------------------------------------------------
__global__ void prep_weights(const float* __restrict__ Win, const float* __restrict__ Wb,
                             const float* __restrict__ Wout, unsigned short* __restrict__ ws) {
  int g = blockIdx.x * 256 + threadIdx.x;
  if (g >= 30720) return;
  const float* W; int N; int local;
  if (g < 2048) { W = Win; N = 256; local = g; }
  else if (g < 26624) {
    int i = g - 2048; int blk = i >> 13; local = i & 8191;
    W = Wb + blk * 65536; N = 256;
  } else { W = Wout; N = 128; local = g - 26624; }
  int f = local >> 6, lane = local & 63;
  int NTL = N >> 4;
  int kc = f / NTL, ntile = f - kc * NTL;
  int n = ntile * 16 + (lane & 15);
  int k0 = kc * 32 + (lane >> 4) * 8;
  unsigned short o[8];
#pragma unroll
  for (int e = 0; e < 8; ++e) o[e] = f2bf(W[(size_t)(k0 + e) * N + n]);
  *reinterpret_cast<uint4*>(ws + (size_t)g * 8) = *reinterpret_cast<uint4*>(o);
}

// ---------------------------------------------------------------------------
// One GEMM layer over 64 rows, 16 waves (2 row-groups x 8 col-groups).
// Wave tile 32 x (16*NT); NT=2 for N=256, NT=1 for N=128.
// MODE: 0 stem relu(ln) ; 1 residual (row-domain register carry) ; 2 head ->
// writes z straight to global Z (no Xb store).
// Phase-B column map (swizzled): thread (wave*4+q, cols {l16*4+64j .. +3}).
// ---------------------------------------------------------------------------
template <int KL, int N, int MODE>
__device__ __forceinline__ void layer(unsigned short* __restrict__ Xb,
                                      float* __restrict__ Yb, float* __restrict__ par,
                                      const unsigned short* __restrict__ Wf,
                                      int tid, int wave, int lane,
                                      const float* __restrict__ bias,
                                      const float* __restrict__ gam,
                                      const float* __restrict__ bet,
                                      float (&xprev)[16],
                                      unsigned short* __restrict__ Z, size_t rowglob) {
  constexpr int NT = N / 128;        // frags per wave per k-slab
  constexpr int NTL = N / 16;        // 16-col tiles across N
  constexpr int KC = KL / 32;        // 32-wide K slabs
  constexpr int J = N / 64;          // 4-col j-groups per thread (4 or 2)
  const int wr = wave >> 3, wc = wave & 7;
  const int q = lane >> 4, l16 = lane & 15;
  const int rowbase = wr * 32;
  const int colbase = wc * 16 * NT;
  const unsigned short* Wl = Wf + lane * 8;

  f32x4 acc[2][NT];
#pragma unroll
  for (int mt = 0; mt < 2; ++mt)
#pragma unroll
    for (int nt = 0; nt < NT; ++nt) acc[mt][nt] = zero4();

  bf16x8 bcur[NT];
#pragma unroll
  for (int nt = 0; nt < NT; ++nt)    // prefetch slab 0 before the barrier
    bcur[nt] = *reinterpret_cast<const bf16x8*>(Wl + (size_t)(wc * NT + nt) * 512);

  __syncthreads();                   // B1: prev phase-B done (Xb/par reusable)
  // stage params (bias|gamma|beta) -> LDS, read in phase B after B2
  if (tid < 3 * N) {
    float v = (tid < N) ? bias[tid] : (tid < 2 * N) ? gam[tid - N] : bet[tid - 2 * N];
    par[tid] = v;
  }
#pragma unroll
  for (int kc = 0; kc < KC; ++kc) {
    bf16x8 bnext[NT];
    if (kc + 1 < KC) {
#pragma unroll
      for (int nt = 0; nt < NT; ++nt)
        bnext[nt] = *reinterpret_cast<const bf16x8*>(
            Wl + (size_t)((kc + 1) * NTL + wc * NT + nt) * 512);
    }
    const int kk = kc * 32 + q * 8;
    bf16x8 a0 = *reinterpret_cast<const bf16x8*>(Xb + (rowbase + l16) * XB_STRIDE + kk);
    bf16x8 a1 = *reinterpret_cast<const bf16x8*>(Xb + (rowbase + 16 + l16) * XB_STRIDE + kk);
#pragma unroll
    for (int nt = 0; nt < NT; ++nt)
      acc[0][nt] = __builtin_amdgcn_mfma_f32_16x16x32_bf16(a0, bcur[nt], acc[0][nt], 0, 0, 0);
#pragma unroll
    for (int nt = 0; nt < NT; ++nt)
      acc[1][nt] = __builtin_amdgcn_mfma_f32_16x16x32_bf16(a1, bcur[nt], acc[1][nt], 0, 0, 0);
    if (kc + 1 < KC) {
#pragma unroll
      for (int nt = 0; nt < NT; ++nt) bcur[nt] = bnext[nt];
    }
  }

  // ---- phase A: raw acc -> Yb fp32 (bank residue 16q+4r+l16 : 2-way, free)
#pragma unroll
  for (int mt = 0; mt < 2; ++mt)
#pragma unroll
    for (int nt = 0; nt < NT; ++nt) {
      const int col = colbase + 16 * nt + l16;
#pragma unroll
      for (int r = 0; r < 4; ++r)
        Yb[(rowbase + 16 * mt + 4 * q + r) * YB_STRIDE + col] = acc[mt][nt][r];
    }
  __syncthreads();                   // B2: Yb + par complete; K-loop Xb reads done

  // ---- phase B: row-domain LN, swizzled cols {l16*4 + 64j .. +3}
  const int row = wave * 4 + q;
  const int cb = l16 * 4;
  float y[4 * J];
#pragma unroll
  for (int j = 0; j < J; ++j)
    *reinterpret_cast<f32x4*>(y + 4 * j) =
        *reinterpret_cast<const f32x4*>(Yb + row * YB_STRIDE + cb + 64 * j);
  float bv[4 * J], gv[4 * J], ev[4 * J];
#pragma unroll
  for (int j = 0; j < J; ++j) {
    *reinterpret_cast<f32x4*>(bv + 4 * j) = *reinterpret_cast<const f32x4*>(par + cb + 64 * j);
    *reinterpret_cast<f32x4*>(gv + 4 * j) = *reinterpret_cast<const f32x4*>(par + N + cb + 64 * j);
    *reinterpret_cast<f32x4*>(ev + 4 * j) = *reinterpret_cast<const f32x4*>(par + 2 * N + cb + 64 * j);
  }
  float s1 = 0.f, s2 = 0.f;
#pragma unroll
  for (int e = 0; e < 4 * J; ++e) {
    y[e] += bv[e];
    s1 += y[e]; s2 = __builtin_fmaf(y[e], y[e], s2);
  }
  s1 = red16(s1); s2 = red16(s2);
  const float mu = s1 * (1.0f / N);
  const float var = s2 * (1.0f / N) - mu * mu;
  const float rstd = rsqrtf(var + 1e-5f);
  const float nmr = -mu * rstd;
#pragma unroll
  for (int j = 0; j < J; ++j) {
    unsigned int pk[2];
#pragma unroll
    for (int i = 0; i < 4; ++i) {
      const int e = 4 * j + i;
      float t = __builtin_fmaf(y[e], rstd, nmr);
      float o = __builtin_fmaf(t, gv[e], ev[e]);
      float xv;
      if constexpr (MODE == 0) { xv = fmaxf(o, 0.f); xprev[e] = xv; }
      else if constexpr (MODE == 1) { xv = xprev[e] + fmaxf(o, 0.f); xprev[e] = xv; }
      else { xv = o; }
      if (i & 1)
        pk[i >> 1] = __builtin_amdgcn_perm(rne16(xv),
                       rne16(__builtin_bit_cast(float, pk[i >> 1])), 0x07060302);
      else
        pk[i >> 1] = __builtin_bit_cast(unsigned int, xv);
    }
    if constexpr (MODE != 2) {       // b64 store; bank residue 2(2q+l16): uniform
      unsigned int* Xw = reinterpret_cast<unsigned int*>(Xb);
      *reinterpret_cast<uint2*>(Xw + row * 132 + 2 * l16 + 32 * j) =
          *reinterpret_cast<uint2*>(pk);
    } else {                         // head: z -> global Z (8B per j-group)
      *reinterpret_cast<uint2*>(Z + (rowglob + row) * 128 + cb + 64 * j) =
          *reinterpret_cast<uint2*>(pk);
    }
  }
}

// ---------------------------------------------------------------------------
// Kernel 1: ResNetMLP over 64 rows (half graph). 2048 blocks x 1024 thr.
// ---------------------------------------------------------------------------
__global__ __attribute__((amdgpu_flat_work_group_size(1024, 1024), amdgpu_waves_per_eu(4)))
void mlp_main(const float* __restrict__ H, const unsigned short* __restrict__ ws,
              const float* __restrict__ b_in, const float* __restrict__ g_in,
              const float* __restrict__ beta_in,
              const float* __restrict__ bb, const float* __restrict__ gb,
              const float* __restrict__ betab,
              const float* __restrict__ b_out, const float* __restrict__ g_out,
              const float* __restrict__ beta_out,
              unsigned short* __restrict__ Z) {
  extern __shared__ char smem[];
  unsigned short* Xb = (unsigned short*)smem;
  float* Yb = (float*)(smem + LDS_YB);
  float* par = (float*)(smem + LDS_PAR);
  const int tid = threadIdx.x;
  const int wave = tid >> 6, lane = tid & 63;
  const size_t rowglob = (size_t)blockIdx.x * 64;

  // stage H (64 x 64 fp32) -> Xb bf16 ; 4 values/thread, packed b64 store
  {
    int row = tid >> 4, c4 = (tid & 15) * 4;
    float4 f = *reinterpret_cast<const float4*>(H + (rowglob + row) * 64 + c4);
    uint2 o;
    o.x = __builtin_amdgcn_perm(rne16(f.y), rne16(f.x), 0x07060302);
    o.y = __builtin_amdgcn_perm(rne16(f.w), rne16(f.z), 0x07060302);
    *reinterpret_cast<uint2*>(Xb + row * XB_STRIDE + c4) = o;
  }

  float xprev[16];
  layer<64, 256, 0>(Xb, Yb, par, ws,           tid, wave, lane, b_in,     g_in,     beta_in,  xprev, Z, rowglob);
  layer<256, 256, 1>(Xb, Yb, par, ws + 16384,  tid, wave, lane, bb,       gb,       betab,    xprev, Z, rowglob);
  layer<256, 256, 1>(Xb, Yb, par, ws + 81920,  tid, wave, lane, bb + 256, gb + 256, betab + 256, xprev, Z, rowglob);
  layer<256, 256, 1>(Xb, Yb, par, ws + 147456, tid, wave, lane, bb + 512, gb + 512, betab + 512, xprev, Z, rowglob);
  layer<256, 128, 2>(Xb, Yb, par, ws + 212992, tid, wave, lane, b_out,    g_out,    beta_out, xprev, Z, rowglob);
}

// ---------------------------------------------------------------------------
// Kernel 2: per-graph gram + mean-distance + softmax + weighted pool.
// 1024 blocks x 512 thr; Z[g] (128x128 bf16) staged to LDS. (R7-verified.)
// ---------------------------------------------------------------------------
__global__ __attribute__((amdgpu_flat_work_group_size(512, 512)))
void pool_main(const unsigned short* __restrict__ Z, float* __restrict__ out) {
  __shared__ unsigned short Zb[128 * ZB_STRIDE];
  __shared__ float sqv[128], sm[128], smw[128];
  const int tid = threadIdx.x;
  const int g = blockIdx.x;
  const int wave = tid >> 6, lane = tid & 63;
  const int q = lane >> 4, l16 = lane & 15;

  {
    int zr = tid >> 2, zc = (tid & 3) * 32;
    const uint4* zp = reinterpret_cast<const uint4*>(Z + ((size_t)g * 128 + zr) * 128 + zc);
    uint4* zd = reinterpret_cast<uint4*>(Zb + zr * ZB_STRIDE + zc);
    zd[0] = zp[0]; zd[1] = zp[1]; zd[2] = zp[2]; zd[3] = zp[3];
  }
  __syncthreads();

  // gram G = Z Z^T : wave owns 16 rows x 128 cols
  f32x4 g2[8];
#pragma unroll
  for (int nt = 0; nt < 8; ++nt) g2[nt] = zero4();
#pragma unroll
  for (int ks = 0; ks < 4; ++ks) {
    int kk = ks * 32 + q * 8;
    bf16x8 a = *reinterpret_cast<const bf16x8*>(Zb + (16 * wave + l16) * ZB_STRIDE + kk);
#pragma unroll
    for (int nt = 0; nt < 8; ++nt) {
      bf16x8 bfr = *reinterpret_cast<const bf16x8*>(Zb + (16 * nt + l16) * ZB_STRIDE + kk);
      g2[nt] = __builtin_amdgcn_mfma_f32_16x16x32_bf16(a, bfr, g2[nt], 0, 0, 0);
    }
  }
  // publish sq_i = G_ii (diag) so d_ii == sqrt(1e-12) exactly like ref
  if ((l16 >> 2) == q) {
#pragma unroll
    for (int nt = 0; nt < 8; ++nt)
      if (nt == wave) {
#pragma unroll
        for (int r = 0; r < 4; ++r)
          if ((l16 & 3) == r) sqv[16 * wave + l16] = g2[nt][r];
      }
  }
  __syncthreads();
  // distances and s_i = mean_j d_ij
  float sqi[4];
#pragma unroll
  for (int r = 0; r < 4; ++r) sqi[r] = sqv[16 * wave + q * 4 + r];
  float sp[4] = {0.f, 0.f, 0.f, 0.f};
#pragma unroll
  for (int nt = 0; nt < 8; ++nt) {
    float sqj = sqv[16 * nt + l16];
#pragma unroll
    for (int r = 0; r < 4; ++r) {
      float d2 = sqi[r] + sqj - 2.0f * g2[nt][r];
      sp[r] += sqrtf(fmaxf(d2, 0.f) + 1e-12f);
    }
  }
#pragma unroll
  for (int d = 1; d < 16; d <<= 1) {
#pragma unroll
    for (int r = 0; r < 4; ++r) { float t = sp[r]; t += __shfl_xor(t, d); sp[r] = t; }
  }
  if (l16 == 0) {
#pragma unroll
    for (int r = 0; r < 4; ++r) sm[16 * wave + q * 4 + r] = sp[r] * (1.0f / 128.0f);
  }
  __syncthreads();
  // softmax(s/TAU) by wave 0 (1/TAU = 4)
  if (wave == 0) {
    float l0 = sm[lane] * 4.0f;
    float l1 = sm[lane + 64] * 4.0f;
    float mx = fmaxf(l0, l1);
#pragma unroll
    for (int d = 1; d < 64; d <<= 1) mx = fmaxf(mx, __shfl_xor(mx, d));
    float e0 = __expf(l0 - mx), e1 = __expf(l1 - mx);
    float ss = e0 + e1;
#pragma unroll
    for (int d = 1; d < 64; d <<= 1) ss += __shfl_xor(ss, d);
    float inv = 1.0f / ss;
    float w0 = e0 * inv, w1 = e1 * inv;
    smw[lane] = w0;
    smw[lane + 64] = w1;
    out[131072 + g * 128 + lane] = w0;
    out[131072 + g * 128 + 64 + lane] = w1;
  }
  __syncthreads();
  // v_loc = sum_i w_i * Z[i,:]
  {
    int c = 16 * wave + l16;
    float acv = 0.f;
#pragma unroll
    for (int i0 = 0; i0 < 32; ++i0) {
      int i = q * 32 + i0;
      acv += smw[i] * bf2f(Zb[i * ZB_STRIDE + c]);
    }
    acv += __shfl_xor(acv, 16);
    acv += __shfl_xor(acv, 32);
    if (q == 0) out[g * 128 + c] = acv;
  }
}

// ---------------------------------------------------------------------------
extern "C" void kernel_launch(void* const* d_in, const int* in_sizes, int n_in,
                              void* d_out, int out_size, void* d_ws, size_t ws_size,
                              hipStream_t stream) {
  (void)in_sizes; (void)n_in; (void)out_size; (void)ws_size;
  const float* H        = (const float*)d_in[0];
  // d_in[1] = batch_ptr (uniform 128/graph, unused)
  const float* W_in     = (const float*)d_in[2];
  const float* b_in     = (const float*)d_in[3];
  const float* g_in     = (const float*)d_in[4];
  const float* beta_in  = (const float*)d_in[5];
  const float* Wb       = (const float*)d_in[6];
  const float* bb       = (const float*)d_in[7];
  const float* gb       = (const float*)d_in[8];
  const float* betab    = (const float*)d_in[9];
  const float* W_out    = (const float*)d_in[10];
  const float* b_out    = (const float*)d_in[11];
  const float* g_out    = (const float*)d_in[12];
  const float* beta_out = (const float*)d_in[13];
  float* out = (float*)d_out;
  unsigned short* ws = (unsigned short*)d_ws;
  unsigned short* Z = ws + 262144;      // 1024*128*128 bf16 = 33.5 MB

  prep_weights<<<120, 256, 0, stream>>>(W_in, Wb, W_out, ws);
  hipFuncSetAttribute(reinterpret_cast<const void*>(mlp_main),
                      hipFuncAttributeMaxDynamicSharedMemorySize, LDS_TOTAL);
  mlp_main<<<2048, 1024, LDS_TOTAL, stream>>>(H, ws, b_in, g_in, beta_in,
                                              bb, gb, betab, b_out, g_out, beta_out, Z);
  pool_main<<<1024, 512, 0, stream>>>(Z, out);
}